// Round 6
// baseline (154.500 us; speedup 1.0000x reference)
//
#include <hip/hip_runtime.h>

// TwelveSitesNN2 R17: barrier-structure cut. Waves own batch rows end-to-end.
//  - Diagnosis: 5 kernels at 66-72us, no pipe saturated, occupancy pinned 34%
//    -> per-block critical path dominated by 5 __syncthreads (each a full
//    vmcnt(0) drain) with 4 lockstep waves.
//  - Change: wave wv owns batch rows 4wv..4wv+3. L1 computes ALL 24 WBT tiles
//    but stores only its 4 columns (+18 MFMA/wave on the idle matrix pipe);
//    h1/PART accesses become wave-private -> L1->L2->PART->pool run with
//    wave_barrier only (in-order DS, lineage-proven). PART gets its own LDS
//    region (kills the overlay anti-dependency barrier).
//  - Barriers: 5 -> 3 (only the all-to-all fc chain keeps __syncthreads).
//  - h1 stride 20, plain q4 reads (R11's proven 2-way-free pattern).
//  - LDS 32000B -> 4 blocks/CU; regs ~= R16 (acc48+bwp48; au chunked 8).

#define LNUM 63
#define BT 16
#define NBT 128   // 2048 / BT
#define WSL 29184 // ushorts per l: [w2T 6656][fw1T 8704][fw2T 4608][WBT 9216]

typedef __attribute__((ext_vector_type(8))) _Float16 half8;
typedef __attribute__((ext_vector_type(2))) _Float16 half2v;
typedef __attribute__((ext_vector_type(4))) float floatx4;
typedef __attribute__((ext_vector_type(4))) unsigned uint4v;

static __device__ __forceinline__ unsigned cvtpk(float a, float b) {
    return __builtin_bit_cast(unsigned, __builtin_amdgcn_cvt_pkrtz(a, b));  // 1 VALU op
}
static __device__ __forceinline__ half2v u2h(unsigned u) { return __builtin_bit_cast(half2v, u); }
static __device__ __forceinline__ float hlo16(unsigned short s) {
    return (float)__builtin_bit_cast(_Float16, s);
}
static __device__ __forceinline__ int w12(int v) { return v >= 12 ? v - 12 : v; }

// LDS layout of fused_nn, dword units (U: 8000 dw = 32000 B):
//   h1     [192 rows=(b*12+s)][20 dw] (16 used = 32 f16 ch)   @0      (wave-own rows)
//   PART   [1024 u=(b*64+ch)][3 chunks]                       @3840   (wave-own quarters)
//   POOLED [16 b][68 dw] (k'-interleaved mean/max f16)        @6912
//   fc overlays (h1 dead after L2): POOL2 ush@0 [16][72], G2 ush@5120 [16][72]
#define O_PART   3840
#define O_POOLDW 6912
#define O_POOLUS 13824
#define O_POOL2  0
#define O_G2     2560

// prep: grid (LNUM, 4). r=0: w2T [o][52dw]; r=1: fw1T [o][68dw] k'-interleaved;
// r=2: fw2T [o][36dw]; r=3: WBT circulant-expanded w1 [384 rows][12 dw]. (unchanged)
__global__ void prep(const float* __restrict__ w2, const float* __restrict__ fw1,
                     const float* __restrict__ fw2, const float* __restrict__ w1,
                     unsigned short* __restrict__ ws) {
    __shared__ float S[8192];
    const int l = blockIdx.x, r = blockIdx.y, t = threadIdx.x;
    if (r == 0) {
        const float4* src = (const float4*)(w2 + (size_t)l * 6144);   // [96][64]
        #pragma unroll
        for (int j = 0; j < 6; ++j) *(float4*)(S + 4 * (t + 256 * j)) = src[t + 256 * j];
        __syncthreads();
        unsigned* dst = (unsigned*)(ws + (size_t)l * WSL);            // 3328 dw
        #pragma unroll
        for (int j = 0; j < 13; ++j) {
            int i = j * 256 + t, o = i / 52, cp = i - 52 * o, c = 2 * cp;
            dst[i] = cvtpk(S[c * 64 + o], S[c * 64 + 64 + o]);
        }
    } else if (r == 1) {
        const float4* src = (const float4*)(fw1 + (size_t)l * 8192);  // [128][64]
        #pragma unroll
        for (int j = 0; j < 8; ++j) *(float4*)(S + 4 * (t + 256 * j)) = src[t + 256 * j];
        __syncthreads();
        unsigned* dst = (unsigned*)(ws + (size_t)l * WSL + 6656);     // 4352 dw
        #pragma unroll
        for (int j = 0; j < 17; ++j) {
            int i = j * 256 + t, o = i / 68, cp = i - 68 * o;
            dst[i] = cvtpk(S[cp * 64 + o], S[(64 + cp) * 64 + o]);    // k'-interleave
        }
    } else if (r == 2) {
        const float4* src = (const float4*)(fw2 + (size_t)l * 4096);  // [64][64]
        #pragma unroll
        for (int j = 0; j < 4; ++j) *(float4*)(S + 4 * (t + 256 * j)) = src[t + 256 * j];
        __syncthreads();
        unsigned* dst = (unsigned*)(ws + (size_t)l * WSL + 15360);    // 2304 dw
        #pragma unroll
        for (int j = 0; j < 9; ++j) {
            int i = j * 256 + t, o = i / 36, cp = i - 36 * o, c = 2 * cp;
            dst[i] = cvtpk(S[c * 64 + o], S[c * 64 + 64 + o]);
        }
    } else {
        // WBT: row = s*32+o (384), k' = site s' (12 dw); dword packs (c=0,c=1).
        if (t < 192) S[t] = w1[(size_t)l * 192 + t];
        __syncthreads();
        unsigned* dst = (unsigned*)(ws + (size_t)l * WSL + 19968);    // 4608 dw
        #pragma unroll
        for (int j = 0; j < 18; ++j) {
            int i = j * 256 + t;               // 0..4607
            int row = i / 12, kp = i - 12 * row;
            int s = row >> 5, o = row & 31;
            int d = kp - s; if (d < 0) d += 12;
            unsigned v = 0;
            if (d == 0)                                    v = cvtpk(S[o],       S[32 + o]);
            else if (d == 1 || d == 3 || d == 9 || d == 11) v = cvtpk(S[64 + o],  S[96 + o]);
            else if (d == 2 || d == 4 || d == 8 || d == 10) v = cvtpk(S[128 + o], S[160 + o]);
            dst[i] = v;
        }
    }
}

__global__ __launch_bounds__(256, 4) void fused_nn(
    const float* __restrict__ zs,  const float* __restrict__ w1,
    const float* __restrict__ fb1, const float* __restrict__ fb2,
    const float* __restrict__ fw3, const float* __restrict__ fb3,
    const unsigned short* __restrict__ ws,
    float* __restrict__ out)
{
    __shared__ __align__(16) unsigned U[8000];
    unsigned short* USH = (unsigned short*)U;

    const int t    = threadIdx.x;
    const int lane = t & 63;
    const int wv   = t >> 6;          // 0..3
    const int n    = lane & 15;
    const int quad = lane >> 4;
    const int l    = blockIdx.x / NBT;
    const int b0   = (blockIdx.x % NBT) * BT;

    // ---------------- loads: own zs rows -> au chunk0 -> (rest interleaved) ---------
    // wave owns batch rows 4wv..4wv+3; xb col n carries batch 4wv+(n&3).
    float4 x0 = {0.f, 0.f, 0.f, 0.f}, x1 = {0.f, 0.f, 0.f, 0.f};
    if (quad < 3) {
        const int gb = b0 + 4 * wv + (n & 3);
        const float* xr = zs + ((size_t)gb * LNUM + l) * 24 + quad * 8;
        x0 = *(const float4*)(xr);
        x1 = *(const float4*)(xr + 4);
    }
    const uint4v* wbt = (const uint4v*)(ws + (size_t)l * WSL + 19968);
    const uint4v* w2q = (const uint4v*)(ws + (size_t)l * WSL);

    uint4v au0[8], au1[8], au2[8];
    #pragma unroll
    for (int i = 0; i < 8; ++i)
        au0[i] = (quad < 3) ? wbt[((i) * 16 + n) * 3 + quad] : (uint4v){0u, 0u, 0u, 0u};
    #pragma unroll
    for (int i = 0; i < 8; ++i)
        au1[i] = (quad < 3) ? wbt[((8 + i) * 16 + n) * 3 + quad] : (uint4v){0u, 0u, 0u, 0u};

    half8 xb;
    {
        uint4v z = {0u, 0u, 0u, 0u};
        if (quad < 3) {
            z.x = cvtpk(x0.x, x0.y); z.y = cvtpk(x0.z, x0.w);
            z.z = cvtpk(x1.x, x1.y); z.w = cvtpk(x1.z, x1.w);
        }
        xb = __builtin_bit_cast(half8, z);
    }

    // ---------------- layer 1: all 24 WBT tiles, keep own 4 batch cols --------------
    // store: dw = ((4wv+n)*12+s)*20 + (rt&1)*8 + 2quad  (n<4), uint2 {pk0,pk1}
    #define L1_TILE(rt, AU)                                                           \
    {                                                                                 \
        floatx4 c = __builtin_amdgcn_mfma_f32_16x16x32_f16(                           \
            __builtin_bit_cast(half8, AU), xb, (floatx4){0.f, 0.f, 0.f, 0.f}, 0, 0, 0);\
        unsigned pk0 = cvtpk(fmaxf(c[0], 0.f), fmaxf(c[1], 0.f));                     \
        unsigned pk1 = cvtpk(fmaxf(c[2], 0.f), fmaxf(c[3], 0.f));                     \
        if (n < 4) {                                                                  \
            const int s_ = (rt) >> 1;                                                 \
            *(uint2*)(U + ((4 * wv + n) * 12 + s_) * 20 + ((rt) & 1) * 8 + 2 * quad)  \
                = make_uint2(pk0, pk1);                                               \
        }                                                                             \
    }
    {
        #pragma unroll
        for (int i = 0; i < 8; ++i) L1_TILE(i, au0[i])
        #pragma unroll
        for (int i = 0; i < 8; ++i)
            au2[i] = (quad < 3) ? wbt[((16 + i) * 16 + n) * 3 + quad] : (uint4v){0u, 0u, 0u, 0u};
        #pragma unroll
        for (int i = 0; i < 8; ++i) L1_TILE(8 + i, au1[i])
    }
    // layer-2 B fragments: 48 VGPRs; latency hides behind remaining L1 work
    uint4v bwp[3][4];
    #pragma unroll
    for (int ks = 0; ks < 3; ++ks)
        #pragma unroll
        for (int nt = 0; nt < 4; ++nt)
            bwp[ks][nt] = w2q[(nt * 16 + n) * 13 + ks * 4 + quad];
    {
        #pragma unroll
        for (int i = 0; i < 8; ++i) L1_TILE(16 + i, au2[i])
    }
    #undef L1_TILE
    // hoist fc bias loads
    const float bias1 = fb1[(size_t)l * 64 + wv * 16 + n];
    const float bias2 = fb2[(size_t)l * 64 + wv * 16 + n];
    __builtin_amdgcn_wave_barrier();   // h1 (wave-own rows) write->read ordering

    // ---------------- layer 2: MFMA f16; rows 48wv..48wv+47 (own batch) ------------
    floatx4 acc[3][4];
    #pragma unroll
    for (int mi = 0; mi < 3; ++mi)
        #pragma unroll
        for (int nt = 0; nt < 4; ++nt) acc[mi][nt] = (floatx4){0.f, 0.f, 0.f, 0.f};
    {
        int rb_[3], si_[3];
        #pragma unroll
        for (int mi = 0; mi < 3; ++mi) {
            int row = 48 * wv + 16 * mi + n;
            int bi = row / 12;
            si_[mi] = row - 12 * bi;
            rb_[mi] = bi * 12;
        }
        const int q4 = quad * 4;
        const int dA[4] = {1, 11, 3, 9};
        const int dB[4] = {2, 10, 4, 8};
        #pragma unroll
        for (int ks = 0; ks < 3; ++ks) {
            half8 af[3];
            #pragma unroll
            for (int mi = 0; mi < 3; ++mi) {
                const int rb = rb_[mi], s = si_[mi];
                if (ks == 0) {
                    af[mi] = *(const half8*)(U + (rb + s) * 20 + q4);
                } else {
                    const int* d = (ks == 1) ? dA : dB;
                    half8 l0 = *(const half8*)(U + (rb + w12(s + d[0])) * 20 + q4);
                    half8 l1 = *(const half8*)(U + (rb + w12(s + d[1])) * 20 + q4);
                    half8 l2 = *(const half8*)(U + (rb + w12(s + d[2])) * 20 + q4);
                    half8 l3 = *(const half8*)(U + (rb + w12(s + d[3])) * 20 + q4);
                    af[mi] = (l0 + l1) + (l2 + l3);
                }
            }
            #pragma unroll
            for (int mi = 0; mi < 3; ++mi)
                #pragma unroll
                for (int nt = 0; nt < 4; ++nt)
                    acc[mi][nt] = __builtin_amdgcn_mfma_f32_16x16x32_f16(
                        af[mi], __builtin_bit_cast(half8, bwp[ks][nt]), acc[mi][nt], 0, 0, 0);
        }
    }
    __builtin_amdgcn_wave_barrier();   // h1 reads done (wave-local)

    // ---------------- pool partials: relu + sum4/max4 -> PART (own quarter) --------
    #pragma unroll
    for (int mi = 0; mi < 3; ++mi) {
        const int rr = 48 * wv + 16 * mi + 4 * quad;   // 4 rows, all within one b
        const int bq = rr / 12;
        const int chk = (rr - 12 * bq) >> 2;
        #pragma unroll
        for (int nt = 0; nt < 4; ++nt) {
            const int ch = nt * 16 + n;
            float r0 = fmaxf(acc[mi][nt][0], 0.f), r1 = fmaxf(acc[mi][nt][1], 0.f);
            float r2 = fmaxf(acc[mi][nt][2], 0.f), r3 = fmaxf(acc[mi][nt][3], 0.f);
            float sm = (r0 + r1) + (r2 + r3);
            float mx = fmaxf(fmaxf(r0, r1), fmaxf(r2, r3));
            U[O_PART + (bq * 64 + ch) * 3 + chk] = cvtpk(sm, mx);
        }
    }
    __builtin_amdgcn_wave_barrier();   // PART write->read is intra-wave

    // ---------------- pool-final: 3 b128 reads, f16 combine -> POOLED --------------
    {
        const unsigned* p = U + O_PART + t * 12;       // units 4t..4t+3 (own wave's b)
        uint4v q0 = *(const uint4v*)(p);
        uint4v q1 = *(const uint4v*)(p + 4);
        uint4v q2 = *(const uint4v*)(p + 8);
        unsigned arr[12] = {q0.x, q0.y, q0.z, q0.w, q1.x, q1.y, q1.z, q1.w,
                            q2.x, q2.y, q2.z, q2.w};
        const int b = t >> 4, ch0 = (t * 4) & 63;
        const _Float16 inv12 = (_Float16)(1.0f / 12.0f);
        unsigned pk[4];
        #pragma unroll
        for (int j = 0; j < 4; ++j) {
            half2v d0 = u2h(arr[3 * j]), d1 = u2h(arr[3 * j + 1]), d2 = u2h(arr[3 * j + 2]);
            _Float16 s = (d0[0] + d1[0]) + d2[0];
            _Float16 m0 = d0[1] > d1[1] ? d0[1] : d1[1];
            _Float16 m  = m0 > d2[1] ? m0 : d2[1];
            half2v pm;
            pm[0] = s * inv12;
            pm[1] = m;
            pk[j] = __builtin_bit_cast(unsigned, pm);
        }
        uint2 w01 = make_uint2(pk[0], pk[1]), w23 = make_uint2(pk[2], pk[3]);
        *(uint2*)(U + O_POOLDW + b * 68 + ch0)     = w01;
        *(uint2*)(U + O_POOLDW + b * 68 + ch0 + 2) = w23;
    }
    __syncthreads();   // barrier 1/3: POOLED is cross-wave for fc1

    // ---------------- fc1: MFMA (M=16, K=128, N=64), B from ws (k'-reordered) ------
    {
        const int o = wv * 16 + n;
        floatx4 a1 = (floatx4){bias1, bias1, bias1, bias1};
        const uint4v* f1q = (const uint4v*)(ws + (size_t)l * WSL + 6656);
        #pragma unroll
        for (int ks = 0; ks < 4; ++ks) {
            half8 av = *(const half8*)(USH + O_POOLUS + n * 136 + ks * 32 + quad * 8);
            uint4v bw = f1q[o * 17 + ks * 4 + quad];
            a1 = __builtin_amdgcn_mfma_f32_16x16x32_f16(av, __builtin_bit_cast(half8, bw), a1, 0, 0, 0);
        }
        #pragma unroll
        for (int i = 0; i < 2; ++i) {
            unsigned pk = cvtpk(fmaxf(a1[2 * i], 0.f), fmaxf(a1[2 * i + 1], 0.f));
            USH[O_POOL2 + (quad * 4 + 2 * i)     * 72 + o] = (unsigned short)(pk & 0xffffu);
            USH[O_POOL2 + (quad * 4 + 2 * i + 1) * 72 + o] = (unsigned short)(pk >> 16);
        }
    }
    __syncthreads();   // barrier 2/3

    // ---------------- fc2: MFMA (M=16, K=64, N=64), B from ws ----------------------
    {
        const int o = wv * 16 + n;
        floatx4 a2 = (floatx4){bias2, bias2, bias2, bias2};
        const uint4v* f2q = (const uint4v*)(ws + (size_t)l * WSL + 15360);
        #pragma unroll
        for (int ks = 0; ks < 2; ++ks) {
            half8 av = *(const half8*)(USH + O_POOL2 + n * 72 + ks * 32 + quad * 8);
            uint4v bw = f2q[o * 9 + ks * 4 + quad];
            a2 = __builtin_amdgcn_mfma_f32_16x16x32_f16(av, __builtin_bit_cast(half8, bw), a2, 0, 0, 0);
        }
        #pragma unroll
        for (int i = 0; i < 2; ++i) {
            unsigned pk = cvtpk(fmaxf(a2[2 * i], 0.f), fmaxf(a2[2 * i + 1], 0.f));
            USH[O_G2 + (quad * 4 + 2 * i)     * 72 + o] = (unsigned short)(pk & 0xffffu);
            USH[O_G2 + (quad * 4 + 2 * i + 1) * 72 + o] = (unsigned short)(pk >> 16);
        }
    }
    __syncthreads();   // barrier 3/3

    // ---------------- fc3 (K=64) + output ------------------------------------------
    if (t < 16) {
        float a = fb3[l];
        const float* w3 = fw3 + (size_t)l * 64;
        #pragma unroll
        for (int c4 = 0; c4 < 16; ++c4) {
            uint2 u2 = *(const uint2*)(USH + O_G2 + t * 72 + c4 * 4);
            float4 w = *(const float4*)(w3 + c4 * 4);
            a += hlo16((unsigned short)(u2.x & 0xffff)) * w.x
               + hlo16((unsigned short)(u2.x >> 16))    * w.y
               + hlo16((unsigned short)(u2.y & 0xffff)) * w.z
               + hlo16((unsigned short)(u2.y >> 16))    * w.w;
        }
        out[(size_t)(b0 + t) * LNUM + l] = a;
    }
}

extern "C" void kernel_launch(void* const* d_in, const int* in_sizes, int n_in,
                              void* d_out, int out_size, void* d_ws, size_t ws_size,
                              hipStream_t stream) {
    const float* zs  = (const float*)d_in[0];
    const float* w1  = (const float*)d_in[1];
    const float* w2  = (const float*)d_in[2];
    const float* fw1 = (const float*)d_in[3];
    const float* fb1 = (const float*)d_in[4];
    const float* fw2 = (const float*)d_in[5];
    const float* fb2 = (const float*)d_in[6];
    const float* fw3 = (const float*)d_in[7];
    const float* fb3 = (const float*)d_in[8];
    float* out = (float*)d_out;
    unsigned short* ws = (unsigned short*)d_ws;

    hipLaunchKernelGGL(prep, dim3(LNUM, 4), dim3(256), 0, stream, w2, fw1, fw2, w1, ws);
    hipLaunchKernelGGL(fused_nn, dim3(LNUM * NBT), dim3(256), 0, stream,
                       zs, w1, fb1, fb2, fw3, fb3, ws, out);
}

// Round 7
// 144.779 us; speedup vs baseline: 1.0671x; 1.0671x over previous
//
#include <hip/hip_runtime.h>

// TwelveSitesNN2 R18: R16 with SITE-MAJOR h1 -> LDS traffic at the bank floor.
//  - h1 row = s*16 + batch (was batch*12 + s). Row stride 20 dw; site stride
//    320 dw == 0 mod 32 banks. Consequences (bank math in journal):
//      L1 MFMA store: banks 20n+2quad -> 4 dw/bank = b64 floor, no XOR.
//      L2 tap reads:  banks 20n+4quad -> 8 dw/bank = b128 floor, zero conflict;
//                     tap row offsets are wave-uniform scalar adds.
//  - L2 M-tile = one site x 16 batches -> pool over sites = in-thread over mi
//    (3 accs); cross-wave 4-way combine via PART[4 planes][b*68+ch] (write
//    2-way free, read at floor).
//  - Same register envelope as R16 (bwp48 + acc48), 5 __syncthreads, LDS 37.1KB
//    -> 4 blocks/CU at __launch_bounds__(256,4).

#define LNUM 63
#define BT 16
#define NBT 128   // 2048 / BT
#define WSL 29184 // ushorts per l: [w2T 6656][fw1T 8704][fw2T 4608][WBT 9216]

typedef __attribute__((ext_vector_type(8))) _Float16 half8;
typedef __attribute__((ext_vector_type(2))) _Float16 half2v;
typedef __attribute__((ext_vector_type(4))) float floatx4;
typedef __attribute__((ext_vector_type(4))) unsigned uint4v;

static __device__ __forceinline__ unsigned cvtpk(float a, float b) {
    return __builtin_bit_cast(unsigned, __builtin_amdgcn_cvt_pkrtz(a, b));  // 1 VALU op
}
static __device__ __forceinline__ half2v u2h(unsigned u) { return __builtin_bit_cast(half2v, u); }
static __device__ __forceinline__ float hlo16(unsigned short s) {
    return (float)__builtin_bit_cast(_Float16, s);
}
static __device__ __forceinline__ int w12(int v) { return v >= 12 ? v - 12 : v; }

// LDS layout of fused_nn, dword units (U: 9280 dw = 37120 B):
//   h1     [192 rows = s*16+b][20 dw] (16 used = 32 f16 ch)        @0
//   PART   [4 wv-planes][16 b][68 dw] (f16 sum,max per dword)      @3840
//   POOLED [16 b][68 dw] (k'-interleaved mean/max f16)             @8192
//   fc overlays (h1 dead after L2): POOL2 ush@0 [16][72], G2 ush@2560 [16][72]
#define O_PART   3840
#define O_POOLDW 8192
#define O_POOLUS 16384
#define O_POOL2  0
#define O_G2     2560

// prep: grid (LNUM, 4). r=0: w2T [o][52dw]; r=1: fw1T [o][68dw] k'-interleaved;
// r=2: fw2T [o][36dw]; r=3: WBT circulant-expanded w1 [384 rows][12 dw]. (unchanged)
__global__ void prep(const float* __restrict__ w2, const float* __restrict__ fw1,
                     const float* __restrict__ fw2, const float* __restrict__ w1,
                     unsigned short* __restrict__ ws) {
    __shared__ float S[8192];
    const int l = blockIdx.x, r = blockIdx.y, t = threadIdx.x;
    if (r == 0) {
        const float4* src = (const float4*)(w2 + (size_t)l * 6144);   // [96][64]
        #pragma unroll
        for (int j = 0; j < 6; ++j) *(float4*)(S + 4 * (t + 256 * j)) = src[t + 256 * j];
        __syncthreads();
        unsigned* dst = (unsigned*)(ws + (size_t)l * WSL);            // 3328 dw
        #pragma unroll
        for (int j = 0; j < 13; ++j) {
            int i = j * 256 + t, o = i / 52, cp = i - 52 * o, c = 2 * cp;
            dst[i] = cvtpk(S[c * 64 + o], S[c * 64 + 64 + o]);
        }
    } else if (r == 1) {
        const float4* src = (const float4*)(fw1 + (size_t)l * 8192);  // [128][64]
        #pragma unroll
        for (int j = 0; j < 8; ++j) *(float4*)(S + 4 * (t + 256 * j)) = src[t + 256 * j];
        __syncthreads();
        unsigned* dst = (unsigned*)(ws + (size_t)l * WSL + 6656);     // 4352 dw
        #pragma unroll
        for (int j = 0; j < 17; ++j) {
            int i = j * 256 + t, o = i / 68, cp = i - 68 * o;
            dst[i] = cvtpk(S[cp * 64 + o], S[(64 + cp) * 64 + o]);    // k'-interleave
        }
    } else if (r == 2) {
        const float4* src = (const float4*)(fw2 + (size_t)l * 4096);  // [64][64]
        #pragma unroll
        for (int j = 0; j < 4; ++j) *(float4*)(S + 4 * (t + 256 * j)) = src[t + 256 * j];
        __syncthreads();
        unsigned* dst = (unsigned*)(ws + (size_t)l * WSL + 15360);    // 2304 dw
        #pragma unroll
        for (int j = 0; j < 9; ++j) {
            int i = j * 256 + t, o = i / 36, cp = i - 36 * o, c = 2 * cp;
            dst[i] = cvtpk(S[c * 64 + o], S[c * 64 + 64 + o]);
        }
    } else {
        // WBT: row = s*32+o (384), k' = site s' (12 dw); dword packs (c=0,c=1).
        if (t < 192) S[t] = w1[(size_t)l * 192 + t];
        __syncthreads();
        unsigned* dst = (unsigned*)(ws + (size_t)l * WSL + 19968);    // 4608 dw
        #pragma unroll
        for (int j = 0; j < 18; ++j) {
            int i = j * 256 + t;               // 0..4607
            int row = i / 12, kp = i - 12 * row;
            int s = row >> 5, o = row & 31;
            int d = kp - s; if (d < 0) d += 12;
            unsigned v = 0;
            if (d == 0)                                    v = cvtpk(S[o],       S[32 + o]);
            else if (d == 1 || d == 3 || d == 9 || d == 11) v = cvtpk(S[64 + o],  S[96 + o]);
            else if (d == 2 || d == 4 || d == 8 || d == 10) v = cvtpk(S[128 + o], S[160 + o]);
            dst[i] = v;
        }
    }
}

__global__ __launch_bounds__(256, 4) void fused_nn(
    const float* __restrict__ zs,  const float* __restrict__ w1,
    const float* __restrict__ fb1, const float* __restrict__ fb2,
    const float* __restrict__ fw3, const float* __restrict__ fb3,
    const unsigned short* __restrict__ ws,
    float* __restrict__ out)
{
    __shared__ __align__(16) unsigned U[9280];
    unsigned short* USH = (unsigned short*)U;

    const int t    = threadIdx.x;
    const int lane = t & 63;
    const int wv   = t >> 6;          // 0..3
    const int n    = lane & 15;
    const int quad = lane >> 4;
    const int l    = blockIdx.x / NBT;
    const int b0   = (blockIdx.x % NBT) * BT;

    // ---------------- issue loads: zs -> WBT -> bwp (vmcnt FIFO friendly) ----------
    float4 x0 = {0.f, 0.f, 0.f, 0.f}, x1 = {0.f, 0.f, 0.f, 0.f};
    if (quad < 3) {
        const float* xr = zs + ((size_t)(b0 + n) * LNUM + l) * 24 + quad * 8;
        x0 = *(const float4*)(xr);
        x1 = *(const float4*)(xr + 4);
    }
    uint4v au[6];
    {
        const uint4v* wbt = (const uint4v*)(ws + (size_t)l * WSL + 19968);
        #pragma unroll
        for (int i = 0; i < 6; ++i) {
            const int rt = 6 * wv + i;
            au[i] = (quad < 3) ? wbt[(rt * 16 + n) * 3 + quad] : (uint4v){0u, 0u, 0u, 0u};
        }
    }
    // layer-2 B fragments: 48 VGPRs, latency hidden behind L1 + barrier (R11/R16)
    uint4v bwp[3][4];
    {
        const uint4v* w2q = (const uint4v*)(ws + (size_t)l * WSL);
        #pragma unroll
        for (int ks = 0; ks < 3; ++ks)
            #pragma unroll
            for (int nt = 0; nt < 4; ++nt)
                bwp[ks][nt] = w2q[(nt * 16 + n) * 13 + ks * 4 + quad];
    }

    // ---------------- layer 1 as MFMA: D[(s,o)][b] = WBT x X ----------------
    half8 xb;
    {
        uint4v z = {0u, 0u, 0u, 0u};
        if (quad < 3) {
            z.x = cvtpk(x0.x, x0.y); z.y = cvtpk(x0.z, x0.w);
            z.z = cvtpk(x1.x, x1.y); z.w = cvtpk(x1.z, x1.w);
        }
        xb = __builtin_bit_cast(half8, z);
    }
    {
        #pragma unroll
        for (int i = 0; i < 6; ++i) {
            const int rt = 6 * wv + i;            // s = rt>>1, o-half = rt&1
            floatx4 c = __builtin_amdgcn_mfma_f32_16x16x32_f16(
                __builtin_bit_cast(half8, au[i]), xb, (floatx4){0.f, 0.f, 0.f, 0.f}, 0, 0, 0);
            unsigned pk0 = cvtpk(fmaxf(c[0], 0.f), fmaxf(c[1], 0.f));
            unsigned pk1 = cvtpk(fmaxf(c[2], 0.f), fmaxf(c[3], 0.f));
            const int s = rt >> 1;
            // site-major: row = s*16 + batch(n); dword = 8*(rt&1) + 2*quad.
            // banks = 20n + 2quad + const -> 4 dw/bank = b64 floor (no XOR).
            *(uint2*)(U + (s * 16 + n) * 20 + (rt & 1) * 8 + 2 * quad) = make_uint2(pk0, pk1);
        }
    }
    // hoist fc bias loads (hide VMEM latency behind layer 2)
    const float bias1 = fb1[(size_t)l * 64 + wv * 16 + n];
    const float bias2 = fb2[(size_t)l * 64 + wv * 16 + n];
    __syncthreads();   // sync 1: h1 cross-wave (taps reach +-4 sites)

    // ---------------- layer 2: MFMA f16; M-tile = site (s = 3wv+mi), 16 batches ----
    floatx4 acc[3][4];
    #pragma unroll
    for (int mi = 0; mi < 3; ++mi)
        #pragma unroll
        for (int nt = 0; nt < 4; ++nt) acc[mi][nt] = (floatx4){0.f, 0.f, 0.f, 0.f};
    {
        const int abase = n * 20 + quad * 4;   // per-lane; site adds 320*s (uniform)
        const int dA[4] = {1, 11, 3, 9};
        const int dB[4] = {2, 10, 4, 8};
        #pragma unroll
        for (int ks = 0; ks < 3; ++ks) {
            half8 af[3];
            #pragma unroll
            for (int mi = 0; mi < 3; ++mi) {
                const int s = 3 * wv + mi;
                if (ks == 0) {
                    af[mi] = *(const half8*)(U + s * 320 + abase);
                } else {
                    const int* d = (ks == 1) ? dA : dB;
                    half8 l0 = *(const half8*)(U + w12(s + d[0]) * 320 + abase);
                    half8 l1 = *(const half8*)(U + w12(s + d[1]) * 320 + abase);
                    half8 l2 = *(const half8*)(U + w12(s + d[2]) * 320 + abase);
                    half8 l3 = *(const half8*)(U + w12(s + d[3]) * 320 + abase);
                    af[mi] = (l0 + l1) + (l2 + l3);
                }
            }
            #pragma unroll
            for (int mi = 0; mi < 3; ++mi)
                #pragma unroll
                for (int nt = 0; nt < 4; ++nt)
                    acc[mi][nt] = __builtin_amdgcn_mfma_f32_16x16x32_f16(
                        af[mi], __builtin_bit_cast(half8, bwp[ks][nt]), acc[mi][nt], 0, 0, 0);
        }
    }

    // ---------------- pool partials: in-thread over mi (3 sites) -> PART plane wv --
    // acc[mi][nt][i] = h2[b=4quad+i][s=3wv+mi][ch=nt*16+n]
    #pragma unroll
    for (int i = 0; i < 4; ++i) {
        const int b = 4 * quad + i;
        #pragma unroll
        for (int nt = 0; nt < 4; ++nt) {
            float r0 = fmaxf(acc[0][nt][i], 0.f);
            float r1 = fmaxf(acc[1][nt][i], 0.f);
            float r2 = fmaxf(acc[2][nt][i], 0.f);
            float sm = (r0 + r1) + r2;
            float mx = fmaxf(fmaxf(r0, r1), r2);
            U[O_PART + wv * 1088 + b * 68 + nt * 16 + n] = cvtpk(sm, mx);
        }
    }
    __syncthreads();   // sync 2: PART cross-wave

    // ---------------- pool-final: 4 plane b128 reads, f16 combine -> POOLED --------
    {
        const int b = t >> 4, ch0 = (t & 15) * 4;
        const unsigned* p = U + O_PART + b * 68 + ch0;
        uint4v q0 = *(const uint4v*)(p);
        uint4v q1 = *(const uint4v*)(p + 1088);
        uint4v q2 = *(const uint4v*)(p + 2176);
        uint4v q3 = *(const uint4v*)(p + 3264);
        const _Float16 inv12 = (_Float16)(1.0f / 12.0f);
        unsigned pk[4];
        #pragma unroll
        for (int j = 0; j < 4; ++j) {
            half2v d0 = u2h(q0[j]), d1 = u2h(q1[j]), d2 = u2h(q2[j]), d3 = u2h(q3[j]);
            _Float16 s = (d0[0] + d1[0]) + (d2[0] + d3[0]);
            _Float16 m0 = d0[1] > d1[1] ? d0[1] : d1[1];
            _Float16 m1 = d2[1] > d3[1] ? d2[1] : d3[1];
            _Float16 m  = m0 > m1 ? m0 : m1;
            half2v pm;
            pm[0] = s * inv12;
            pm[1] = m;
            pk[j] = __builtin_bit_cast(unsigned, pm);
        }
        uint2 w01 = make_uint2(pk[0], pk[1]), w23 = make_uint2(pk[2], pk[3]);
        *(uint2*)(U + O_POOLDW + b * 68 + ch0)     = w01;
        *(uint2*)(U + O_POOLDW + b * 68 + ch0 + 2) = w23;
    }
    __syncthreads();   // sync 3: POOLED cross-wave for fc1

    // ---------------- fc1: MFMA (M=16, K=128, N=64), B from ws (k'-reordered) ------
    {
        const int o = wv * 16 + n;
        floatx4 a1 = (floatx4){bias1, bias1, bias1, bias1};
        const uint4v* f1q = (const uint4v*)(ws + (size_t)l * WSL + 6656);
        #pragma unroll
        for (int ks = 0; ks < 4; ++ks) {
            half8 av = *(const half8*)(USH + O_POOLUS + n * 136 + ks * 32 + quad * 8);
            uint4v bw = f1q[o * 17 + ks * 4 + quad];
            a1 = __builtin_amdgcn_mfma_f32_16x16x32_f16(av, __builtin_bit_cast(half8, bw), a1, 0, 0, 0);
        }
        #pragma unroll
        for (int i = 0; i < 2; ++i) {
            unsigned pk = cvtpk(fmaxf(a1[2 * i], 0.f), fmaxf(a1[2 * i + 1], 0.f));
            USH[O_POOL2 + (quad * 4 + 2 * i)     * 72 + o] = (unsigned short)(pk & 0xffffu);
            USH[O_POOL2 + (quad * 4 + 2 * i + 1) * 72 + o] = (unsigned short)(pk >> 16);
        }
    }
    __syncthreads();   // sync 4

    // ---------------- fc2: MFMA (M=16, K=64, N=64), B from ws ----------------------
    {
        const int o = wv * 16 + n;
        floatx4 a2 = (floatx4){bias2, bias2, bias2, bias2};
        const uint4v* f2q = (const uint4v*)(ws + (size_t)l * WSL + 15360);
        #pragma unroll
        for (int ks = 0; ks < 2; ++ks) {
            half8 av = *(const half8*)(USH + O_POOL2 + n * 72 + ks * 32 + quad * 8);
            uint4v bw = f2q[o * 9 + ks * 4 + quad];
            a2 = __builtin_amdgcn_mfma_f32_16x16x32_f16(av, __builtin_bit_cast(half8, bw), a2, 0, 0, 0);
        }
        #pragma unroll
        for (int i = 0; i < 2; ++i) {
            unsigned pk = cvtpk(fmaxf(a2[2 * i], 0.f), fmaxf(a2[2 * i + 1], 0.f));
            USH[O_G2 + (quad * 4 + 2 * i)     * 72 + o] = (unsigned short)(pk & 0xffffu);
            USH[O_G2 + (quad * 4 + 2 * i + 1) * 72 + o] = (unsigned short)(pk >> 16);
        }
    }
    __syncthreads();   // sync 5

    // ---------------- fc3 (K=64) + output ------------------------------------------
    if (t < 16) {
        float a = fb3[l];
        const float* w3 = fw3 + (size_t)l * 64;
        #pragma unroll
        for (int c4 = 0; c4 < 16; ++c4) {
            uint2 u2 = *(const uint2*)(USH + O_G2 + t * 72 + c4 * 4);
            float4 w = *(const float4*)(w3 + c4 * 4);
            a += hlo16((unsigned short)(u2.x & 0xffff)) * w.x
               + hlo16((unsigned short)(u2.x >> 16))    * w.y
               + hlo16((unsigned short)(u2.y & 0xffff)) * w.z
               + hlo16((unsigned short)(u2.y >> 16))    * w.w;
        }
        out[(size_t)(b0 + t) * LNUM + l] = a;
    }
}

extern "C" void kernel_launch(void* const* d_in, const int* in_sizes, int n_in,
                              void* d_out, int out_size, void* d_ws, size_t ws_size,
                              hipStream_t stream) {
    const float* zs  = (const float*)d_in[0];
    const float* w1  = (const float*)d_in[1];
    const float* w2  = (const float*)d_in[2];
    const float* fw1 = (const float*)d_in[3];
    const float* fb1 = (const float*)d_in[4];
    const float* fw2 = (const float*)d_in[5];
    const float* fb2 = (const float*)d_in[6];
    const float* fw3 = (const float*)d_in[7];
    const float* fb3 = (const float*)d_in[8];
    float* out = (float*)d_out;
    unsigned short* ws = (unsigned short*)d_ws;

    hipLaunchKernelGGL(prep, dim3(LNUM, 4), dim3(256), 0, stream, w2, fw1, fw2, w1, ws);
    hipLaunchKernelGGL(fused_nn, dim3(LNUM * NBT), dim3(256), 0, stream,
                       zs, w1, fb1, fb2, fw3, fb3, ws, out);
}

// Round 8
// 135.859 us; speedup vs baseline: 1.1372x; 1.0657x over previous
//
#include <hip/hip_runtime.h>

// TwelveSitesNN2 R19: R18 (site-major h1, bank-floor LDS) + spill fix.
//  - R18 verdict: conflicts 9.16M -> 3.87M (layout math confirmed) BUT
//    WRITE_SIZE 647KB -> 15MB = ~2 dw/thread scratch spill under the
//    (256,4) 128-reg cap; spill cost (+13.6us-eq) ate the conflict win.
//  - Fix: __launch_bounds__(256,3) -> ~170-reg budget. Free: measured
//    occupancy is already ~11 waves/CU (<3 blocks) and LDS (37.4KB) caps
//    residency at 4 blocks regardless.
//  - Everything else byte-identical to R18.

#define LNUM 63
#define BT 16
#define NBT 128   // 2048 / BT
#define WSL 29184 // ushorts per l: [w2T 6656][fw1T 8704][fw2T 4608][WBT 9216]

typedef __attribute__((ext_vector_type(8))) _Float16 half8;
typedef __attribute__((ext_vector_type(2))) _Float16 half2v;
typedef __attribute__((ext_vector_type(4))) float floatx4;
typedef __attribute__((ext_vector_type(4))) unsigned uint4v;

static __device__ __forceinline__ unsigned cvtpk(float a, float b) {
    return __builtin_bit_cast(unsigned, __builtin_amdgcn_cvt_pkrtz(a, b));  // 1 VALU op
}
static __device__ __forceinline__ half2v u2h(unsigned u) { return __builtin_bit_cast(half2v, u); }
static __device__ __forceinline__ float hlo16(unsigned short s) {
    return (float)__builtin_bit_cast(_Float16, s);
}
static __device__ __forceinline__ int w12(int v) { return v >= 12 ? v - 12 : v; }

// LDS layout of fused_nn, dword units (U: 9280 dw = 37120 B):
//   h1     [192 rows = s*16+b][20 dw] (16 used = 32 f16 ch)        @0
//   PART   [4 wv-planes][16 b][68 dw] (f16 sum,max per dword)      @3840
//   POOLED [16 b][68 dw] (k'-interleaved mean/max f16)             @8192
//   fc overlays (h1 dead after L2): POOL2 ush@0 [16][72], G2 ush@2560 [16][72]
#define O_PART   3840
#define O_POOLDW 8192
#define O_POOLUS 16384
#define O_POOL2  0
#define O_G2     2560

// prep: grid (LNUM, 4). r=0: w2T [o][52dw]; r=1: fw1T [o][68dw] k'-interleaved;
// r=2: fw2T [o][36dw]; r=3: WBT circulant-expanded w1 [384 rows][12 dw]. (unchanged)
__global__ void prep(const float* __restrict__ w2, const float* __restrict__ fw1,
                     const float* __restrict__ fw2, const float* __restrict__ w1,
                     unsigned short* __restrict__ ws) {
    __shared__ float S[8192];
    const int l = blockIdx.x, r = blockIdx.y, t = threadIdx.x;
    if (r == 0) {
        const float4* src = (const float4*)(w2 + (size_t)l * 6144);   // [96][64]
        #pragma unroll
        for (int j = 0; j < 6; ++j) *(float4*)(S + 4 * (t + 256 * j)) = src[t + 256 * j];
        __syncthreads();
        unsigned* dst = (unsigned*)(ws + (size_t)l * WSL);            // 3328 dw
        #pragma unroll
        for (int j = 0; j < 13; ++j) {
            int i = j * 256 + t, o = i / 52, cp = i - 52 * o, c = 2 * cp;
            dst[i] = cvtpk(S[c * 64 + o], S[c * 64 + 64 + o]);
        }
    } else if (r == 1) {
        const float4* src = (const float4*)(fw1 + (size_t)l * 8192);  // [128][64]
        #pragma unroll
        for (int j = 0; j < 8; ++j) *(float4*)(S + 4 * (t + 256 * j)) = src[t + 256 * j];
        __syncthreads();
        unsigned* dst = (unsigned*)(ws + (size_t)l * WSL + 6656);     // 4352 dw
        #pragma unroll
        for (int j = 0; j < 17; ++j) {
            int i = j * 256 + t, o = i / 68, cp = i - 68 * o;
            dst[i] = cvtpk(S[cp * 64 + o], S[(64 + cp) * 64 + o]);    // k'-interleave
        }
    } else if (r == 2) {
        const float4* src = (const float4*)(fw2 + (size_t)l * 4096);  // [64][64]
        #pragma unroll
        for (int j = 0; j < 4; ++j) *(float4*)(S + 4 * (t + 256 * j)) = src[t + 256 * j];
        __syncthreads();
        unsigned* dst = (unsigned*)(ws + (size_t)l * WSL + 15360);    // 2304 dw
        #pragma unroll
        for (int j = 0; j < 9; ++j) {
            int i = j * 256 + t, o = i / 36, cp = i - 36 * o, c = 2 * cp;
            dst[i] = cvtpk(S[c * 64 + o], S[c * 64 + 64 + o]);
        }
    } else {
        // WBT: row = s*32+o (384), k' = site s' (12 dw); dword packs (c=0,c=1).
        if (t < 192) S[t] = w1[(size_t)l * 192 + t];
        __syncthreads();
        unsigned* dst = (unsigned*)(ws + (size_t)l * WSL + 19968);    // 4608 dw
        #pragma unroll
        for (int j = 0; j < 18; ++j) {
            int i = j * 256 + t;               // 0..4607
            int row = i / 12, kp = i - 12 * row;
            int s = row >> 5, o = row & 31;
            int d = kp - s; if (d < 0) d += 12;
            unsigned v = 0;
            if (d == 0)                                    v = cvtpk(S[o],       S[32 + o]);
            else if (d == 1 || d == 3 || d == 9 || d == 11) v = cvtpk(S[64 + o],  S[96 + o]);
            else if (d == 2 || d == 4 || d == 8 || d == 10) v = cvtpk(S[128 + o], S[160 + o]);
            dst[i] = v;
        }
    }
}

__global__ __launch_bounds__(256, 3) void fused_nn(
    const float* __restrict__ zs,  const float* __restrict__ w1,
    const float* __restrict__ fb1, const float* __restrict__ fb2,
    const float* __restrict__ fw3, const float* __restrict__ fb3,
    const unsigned short* __restrict__ ws,
    float* __restrict__ out)
{
    __shared__ __align__(16) unsigned U[9280];
    unsigned short* USH = (unsigned short*)U;

    const int t    = threadIdx.x;
    const int lane = t & 63;
    const int wv   = t >> 6;          // 0..3
    const int n    = lane & 15;
    const int quad = lane >> 4;
    const int l    = blockIdx.x / NBT;
    const int b0   = (blockIdx.x % NBT) * BT;

    // ---------------- issue loads: zs -> WBT -> bwp (vmcnt FIFO friendly) ----------
    float4 x0 = {0.f, 0.f, 0.f, 0.f}, x1 = {0.f, 0.f, 0.f, 0.f};
    if (quad < 3) {
        const float* xr = zs + ((size_t)(b0 + n) * LNUM + l) * 24 + quad * 8;
        x0 = *(const float4*)(xr);
        x1 = *(const float4*)(xr + 4);
    }
    uint4v au[6];
    {
        const uint4v* wbt = (const uint4v*)(ws + (size_t)l * WSL + 19968);
        #pragma unroll
        for (int i = 0; i < 6; ++i) {
            const int rt = 6 * wv + i;
            au[i] = (quad < 3) ? wbt[(rt * 16 + n) * 3 + quad] : (uint4v){0u, 0u, 0u, 0u};
        }
    }
    // layer-2 B fragments: 48 VGPRs, latency hidden behind L1 + barrier (R11/R16)
    uint4v bwp[3][4];
    {
        const uint4v* w2q = (const uint4v*)(ws + (size_t)l * WSL);
        #pragma unroll
        for (int ks = 0; ks < 3; ++ks)
            #pragma unroll
            for (int nt = 0; nt < 4; ++nt)
                bwp[ks][nt] = w2q[(nt * 16 + n) * 13 + ks * 4 + quad];
    }

    // ---------------- layer 1 as MFMA: D[(s,o)][b] = WBT x X ----------------
    half8 xb;
    {
        uint4v z = {0u, 0u, 0u, 0u};
        if (quad < 3) {
            z.x = cvtpk(x0.x, x0.y); z.y = cvtpk(x0.z, x0.w);
            z.z = cvtpk(x1.x, x1.y); z.w = cvtpk(x1.z, x1.w);
        }
        xb = __builtin_bit_cast(half8, z);
    }
    {
        #pragma unroll
        for (int i = 0; i < 6; ++i) {
            const int rt = 6 * wv + i;            // s = rt>>1, o-half = rt&1
            floatx4 c = __builtin_amdgcn_mfma_f32_16x16x32_f16(
                __builtin_bit_cast(half8, au[i]), xb, (floatx4){0.f, 0.f, 0.f, 0.f}, 0, 0, 0);
            unsigned pk0 = cvtpk(fmaxf(c[0], 0.f), fmaxf(c[1], 0.f));
            unsigned pk1 = cvtpk(fmaxf(c[2], 0.f), fmaxf(c[3], 0.f));
            const int s = rt >> 1;
            // site-major: row = s*16 + batch(n); dword = 8*(rt&1) + 2*quad.
            // banks = 20n + 2quad + const -> 4 dw/bank = b64 floor (no XOR).
            *(uint2*)(U + (s * 16 + n) * 20 + (rt & 1) * 8 + 2 * quad) = make_uint2(pk0, pk1);
        }
    }
    // hoist fc bias loads (hide VMEM latency behind layer 2)
    const float bias1 = fb1[(size_t)l * 64 + wv * 16 + n];
    const float bias2 = fb2[(size_t)l * 64 + wv * 16 + n];
    __syncthreads();   // sync 1: h1 cross-wave (taps reach +-4 sites)

    // ---------------- layer 2: MFMA f16; M-tile = site (s = 3wv+mi), 16 batches ----
    floatx4 acc[3][4];
    #pragma unroll
    for (int mi = 0; mi < 3; ++mi)
        #pragma unroll
        for (int nt = 0; nt < 4; ++nt) acc[mi][nt] = (floatx4){0.f, 0.f, 0.f, 0.f};
    {
        const int abase = n * 20 + quad * 4;   // per-lane; site adds 320*s (uniform)
        const int dA[4] = {1, 11, 3, 9};
        const int dB[4] = {2, 10, 4, 8};
        #pragma unroll
        for (int ks = 0; ks < 3; ++ks) {
            half8 af[3];
            #pragma unroll
            for (int mi = 0; mi < 3; ++mi) {
                const int s = 3 * wv + mi;
                if (ks == 0) {
                    af[mi] = *(const half8*)(U + s * 320 + abase);
                } else {
                    const int* d = (ks == 1) ? dA : dB;
                    half8 l0 = *(const half8*)(U + w12(s + d[0]) * 320 + abase);
                    half8 l1 = *(const half8*)(U + w12(s + d[1]) * 320 + abase);
                    half8 l2 = *(const half8*)(U + w12(s + d[2]) * 320 + abase);
                    half8 l3 = *(const half8*)(U + w12(s + d[3]) * 320 + abase);
                    af[mi] = (l0 + l1) + (l2 + l3);
                }
            }
            #pragma unroll
            for (int mi = 0; mi < 3; ++mi)
                #pragma unroll
                for (int nt = 0; nt < 4; ++nt)
                    acc[mi][nt] = __builtin_amdgcn_mfma_f32_16x16x32_f16(
                        af[mi], __builtin_bit_cast(half8, bwp[ks][nt]), acc[mi][nt], 0, 0, 0);
        }
    }

    // ---------------- pool partials: in-thread over mi (3 sites) -> PART plane wv --
    // acc[mi][nt][i] = h2[b=4quad+i][s=3wv+mi][ch=nt*16+n]
    #pragma unroll
    for (int i = 0; i < 4; ++i) {
        const int b = 4 * quad + i;
        #pragma unroll
        for (int nt = 0; nt < 4; ++nt) {
            float r0 = fmaxf(acc[0][nt][i], 0.f);
            float r1 = fmaxf(acc[1][nt][i], 0.f);
            float r2 = fmaxf(acc[2][nt][i], 0.f);
            float sm = (r0 + r1) + r2;
            float mx = fmaxf(fmaxf(r0, r1), r2);
            U[O_PART + wv * 1088 + b * 68 + nt * 16 + n] = cvtpk(sm, mx);
        }
    }
    __syncthreads();   // sync 2: PART cross-wave

    // ---------------- pool-final: 4 plane b128 reads, f16 combine -> POOLED --------
    {
        const int b = t >> 4, ch0 = (t & 15) * 4;
        const unsigned* p = U + O_PART + b * 68 + ch0;
        uint4v q0 = *(const uint4v*)(p);
        uint4v q1 = *(const uint4v*)(p + 1088);
        uint4v q2 = *(const uint4v*)(p + 2176);
        uint4v q3 = *(const uint4v*)(p + 3264);
        const _Float16 inv12 = (_Float16)(1.0f / 12.0f);
        unsigned pk[4];
        #pragma unroll
        for (int j = 0; j < 4; ++j) {
            half2v d0 = u2h(q0[j]), d1 = u2h(q1[j]), d2 = u2h(q2[j]), d3 = u2h(q3[j]);
            _Float16 s = (d0[0] + d1[0]) + (d2[0] + d3[0]);
            _Float16 m0 = d0[1] > d1[1] ? d0[1] : d1[1];
            _Float16 m1 = d2[1] > d3[1] ? d2[1] : d3[1];
            _Float16 m  = m0 > m1 ? m0 : m1;
            half2v pm;
            pm[0] = s * inv12;
            pm[1] = m;
            pk[j] = __builtin_bit_cast(unsigned, pm);
        }
        uint2 w01 = make_uint2(pk[0], pk[1]), w23 = make_uint2(pk[2], pk[3]);
        *(uint2*)(U + O_POOLDW + b * 68 + ch0)     = w01;
        *(uint2*)(U + O_POOLDW + b * 68 + ch0 + 2) = w23;
    }
    __syncthreads();   // sync 3: POOLED cross-wave for fc1

    // ---------------- fc1: MFMA (M=16, K=128, N=64), B from ws (k'-reordered) ------
    {
        const int o = wv * 16 + n;
        floatx4 a1 = (floatx4){bias1, bias1, bias1, bias1};
        const uint4v* f1q = (const uint4v*)(ws + (size_t)l * WSL + 6656);
        #pragma unroll
        for (int ks = 0; ks < 4; ++ks) {
            half8 av = *(const half8*)(USH + O_POOLUS + n * 136 + ks * 32 + quad * 8);
            uint4v bw = f1q[o * 17 + ks * 4 + quad];
            a1 = __builtin_amdgcn_mfma_f32_16x16x32_f16(av, __builtin_bit_cast(half8, bw), a1, 0, 0, 0);
        }
        #pragma unroll
        for (int i = 0; i < 2; ++i) {
            unsigned pk = cvtpk(fmaxf(a1[2 * i], 0.f), fmaxf(a1[2 * i + 1], 0.f));
            USH[O_POOL2 + (quad * 4 + 2 * i)     * 72 + o] = (unsigned short)(pk & 0xffffu);
            USH[O_POOL2 + (quad * 4 + 2 * i + 1) * 72 + o] = (unsigned short)(pk >> 16);
        }
    }
    __syncthreads();   // sync 4

    // ---------------- fc2: MFMA (M=16, K=64, N=64), B from ws ----------------------
    {
        const int o = wv * 16 + n;
        floatx4 a2 = (floatx4){bias2, bias2, bias2, bias2};
        const uint4v* f2q = (const uint4v*)(ws + (size_t)l * WSL + 15360);
        #pragma unroll
        for (int ks = 0; ks < 2; ++ks) {
            half8 av = *(const half8*)(USH + O_POOL2 + n * 72 + ks * 32 + quad * 8);
            uint4v bw = f2q[o * 9 + ks * 4 + quad];
            a2 = __builtin_amdgcn_mfma_f32_16x16x32_f16(av, __builtin_bit_cast(half8, bw), a2, 0, 0, 0);
        }
        #pragma unroll
        for (int i = 0; i < 2; ++i) {
            unsigned pk = cvtpk(fmaxf(a2[2 * i], 0.f), fmaxf(a2[2 * i + 1], 0.f));
            USH[O_G2 + (quad * 4 + 2 * i)     * 72 + o] = (unsigned short)(pk & 0xffffu);
            USH[O_G2 + (quad * 4 + 2 * i + 1) * 72 + o] = (unsigned short)(pk >> 16);
        }
    }
    __syncthreads();   // sync 5

    // ---------------- fc3 (K=64) + output ------------------------------------------
    if (t < 16) {
        float a = fb3[l];
        const float* w3 = fw3 + (size_t)l * 64;
        #pragma unroll
        for (int c4 = 0; c4 < 16; ++c4) {
            uint2 u2 = *(const uint2*)(USH + O_G2 + t * 72 + c4 * 4);
            float4 w = *(const float4*)(w3 + c4 * 4);
            a += hlo16((unsigned short)(u2.x & 0xffff)) * w.x
               + hlo16((unsigned short)(u2.x >> 16))    * w.y
               + hlo16((unsigned short)(u2.y & 0xffff)) * w.z
               + hlo16((unsigned short)(u2.y >> 16))    * w.w;
        }
        out[(size_t)(b0 + t) * LNUM + l] = a;
    }
}

extern "C" void kernel_launch(void* const* d_in, const int* in_sizes, int n_in,
                              void* d_out, int out_size, void* d_ws, size_t ws_size,
                              hipStream_t stream) {
    const float* zs  = (const float*)d_in[0];
    const float* w1  = (const float*)d_in[1];
    const float* w2  = (const float*)d_in[2];
    const float* fw1 = (const float*)d_in[3];
    const float* fb1 = (const float*)d_in[4];
    const float* fw2 = (const float*)d_in[5];
    const float* fb2 = (const float*)d_in[6];
    const float* fw3 = (const float*)d_in[7];
    const float* fb3 = (const float*)d_in[8];
    float* out = (float*)d_out;
    unsigned short* ws = (unsigned short*)d_ws;

    hipLaunchKernelGGL(prep, dim3(LNUM, 4), dim3(256), 0, stream, w2, fw1, fw2, w1, ws);
    hipLaunchKernelGGL(fused_nn, dim3(LNUM * NBT), dim3(256), 0, stream,
                       zs, w1, fb1, fb2, fw3, fb3, ws, out);
}